// Round 7
// baseline (629.782 us; speedup 1.0000x reference)
//
#include <hip/hip_runtime.h>

#define N_IMG 128
#define BINS 128
#define HW_ELEMS (1 << 20)                       // 1024*1024 per image
#define NBLOCKS 1024                             // 4 blocks/CU x 256 CUs (co-resident)
#define CHUNK_ELEMS 4096                         // 16 KB chunk staged in LDS
#define CHUNK_V4 (CHUNK_ELEMS / 4)               // 1024 float4
#define CHUNKS_PER_IMG (HW_ELEMS / CHUNK_ELEMS)  // 256
#define IMGS_PER_GROUP (NBLOCKS / CHUNKS_PER_IMG)// 4
#define NGROUPS (N_IMG / IMGS_PER_GROUP)         // 32
#define NCOPY 8                                  // privatized LDS hist copies (32 lanes each)
#define HPAD 132                                 // 132 % 32 = 4 -> phase-shifted banks
#define FLAG_STRIDE 32                           // 128B per image flag line

typedef float f32x4 __attribute__((ext_vector_type(4)));

// Fence-free device-scope primitives (round 6 lesson: acquire/release fences
// storm the per-XCD L2 with invalidates; relaxed RMWs execute at the
// coherence point with no cache maintenance).
__device__ __forceinline__ unsigned rmw_poll(unsigned* p) {
    return __hip_atomic_fetch_or(p, 0u, __ATOMIC_RELAXED, __HIP_MEMORY_SCOPE_AGENT);
}
__device__ __forceinline__ void rmw_store(unsigned* p, unsigned v) {
    __hip_atomic_exchange(p, v, __ATOMIC_RELAXED, __HIP_MEMORY_SCOPE_AGENT);
}
__device__ __forceinline__ int rmw_inc(int* p) {
    return __hip_atomic_fetch_add(p, 1, __ATOMIC_RELAXED, __HIP_MEMORY_SCOPE_AGENT);
}

// Software-pipelined fused kernel:
//   round r: hist+stage group r into buf[r&1]  |  scale group r-1 from buf[(r-1)&1]
// The flag polled in round r was produced during round r-1 -> no convoy.
// x crosses HBM exactly once (1.0 GB total traffic vs 1.5 GB unfused).
__global__ __launch_bounds__(256, 4) void fused_kernel(
    const float* __restrict__ x,
    const float* __restrict__ W1, const float* __restrict__ b1,
    const float* __restrict__ W2, const float* __restrict__ b2,
    const float* __restrict__ W3, const float* __restrict__ b3,
    const float* __restrict__ W4, const float* __restrict__ b4,
    float* __restrict__ out,
    int* __restrict__ hist, int* __restrict__ done,
    unsigned* __restrict__ flags)                // [img*32]=ready, [img*32+1]=w bits
{
    __shared__ float stage[2][CHUNK_ELEMS];      // 32 KB
    __shared__ int   lh[NCOPY * HPAD];           // 4.2 KB
    __shared__ float h0[BINS], a1[32], a2[64], a3[BINS];
    __shared__ float wbc;
    __shared__ int   retsh;

    const int t        = threadIdx.x;
    const int g        = blockIdx.x;
    const int cpy      = t >> 5;                 // 8 copies, 32 lanes each
    const int slot_img = g >> 8;                 // 0..3 within group
    const int cin      = g & (CHUNKS_PER_IMG - 1);

    for (int r = 0; r <= NGROUPS; ++r) {
        // ---------- A: histogram + stage current group's chunk ----------
        if (r < NGROUPS) {
            const int img = r * IMGS_PER_GROUP + slot_img;
            for (int i = t; i < NCOPY * HPAD; i += 256) lh[i] = 0;
            __syncthreads();

            const f32x4* src = (const f32x4*)(x + (size_t)img * HW_ELEMS
                                                + (size_t)cin * CHUNK_ELEMS);
            f32x4* stg = (f32x4*)stage[r & 1];
            #pragma unroll
            for (int j = 0; j < CHUNK_V4 / 256; ++j) {   // 4 iters
                f32x4 v = src[j * 256 + t];
                stg[j * 256 + t] = v;
                #pragma unroll
                for (int k = 0; k < 4; ++k) {
                    float f = v[k];
                    if (f >= 0.0f && f <= 1.0f) {
                        int b = (int)(f * 128.0f);
                        b = b > 127 ? 127 : b;
                        atomicAdd(&lh[cpy * HPAD + b], 1);
                    }
                }
            }
            __syncthreads();

            if (t < BINS) {
                int ssum = 0;
                #pragma unroll
                for (int c = 0; c < NCOPY; ++c) ssum += lh[c * HPAD + t];
                atomicAdd(&hist[img * BINS + t], ssum);   // device-scope RMW
            }
            __syncthreads();          // drains vmcnt -> this block's adds complete
            if (t == 0) retsh = rmw_inc(&done[img]);
            __syncthreads();
            const int ret = retsh;    // block-uniform

            // ---------- B: 256th finisher runs the MLP (concurrent w/ others' C) ----------
            if (ret == CHUNKS_PER_IMG - 1) {
                if (t < BINS) {
                    int hv = __hip_atomic_load(&hist[img * BINS + t],
                                               __ATOMIC_RELAXED, __HIP_MEMORY_SCOPE_AGENT);
                    h0[t] = (float)hv;
                }
                __syncthreads();
                if (t < 32) {
                    float acc = b1[t];
                    #pragma unroll 8
                    for (int i = 0; i < 128; ++i) acc += h0[i] * W1[i * 32 + t];
                    a1[t] = fmaxf(acc, 0.0f);
                }
                __syncthreads();
                if (t < 64) {
                    float acc = b2[t];
                    #pragma unroll 8
                    for (int i = 0; i < 32; ++i) acc += a1[i] * W2[i * 64 + t];
                    a2[t] = fmaxf(acc, 0.0f);
                }
                __syncthreads();
                if (t < 128) {
                    float acc = b3[t];
                    #pragma unroll 8
                    for (int i = 0; i < 64; ++i) acc += a2[i] * W3[i * 128 + t];
                    a3[t] = fmaxf(acc, 0.0f);
                }
                __syncthreads();
                if (t < 64) {
                    float p = a3[t] * W4[t] + a3[t + 64] * W4[t + 64];
                    #pragma unroll
                    for (int off = 32; off > 0; off >>= 1)
                        p += __shfl_down(p, off, 64);
                    if (t == 0)
                        rmw_store(&flags[img * FLAG_STRIDE + 1],
                                  __float_as_uint(p + b4[0]));
                }
                __syncthreads();      // drains vmcnt -> w value complete
                if (t == 0) rmw_store(&flags[img * FLAG_STRIDE], 1u);
                __syncthreads();
            }
        }

        // ---------- C: scale PREVIOUS group's chunk from LDS ----------
        if (r > 0) {
            const int img = (r - 1) * IMGS_PER_GROUP + slot_img;
            if (t == 0) {
                while (rmw_poll(&flags[img * FLAG_STRIDE]) == 0u)
                    __builtin_amdgcn_s_sleep(8);         // ~0.2us; usually hits 1st try
                wbc = __uint_as_float(rmw_poll(&flags[img * FLAG_STRIDE + 1]));
            }
            __syncthreads();
            const float w = wbc;
            f32x4* dst = (f32x4*)(out + (size_t)img * HW_ELEMS
                                      + (size_t)cin * CHUNK_ELEMS);
            const f32x4* stg = (const f32x4*)stage[(r - 1) & 1];
            #pragma unroll
            for (int j = 0; j < CHUNK_V4 / 256; ++j) {
                f32x4 v = stg[j * 256 + t];
                v *= w;
                __builtin_nontemporal_store(v, &dst[j * 256 + t]);
            }
            __syncthreads();          // wbc + stage[(r-1)&1] reuse protection
        }
    }
}

extern "C" void kernel_launch(void* const* d_in, const int* in_sizes, int n_in,
                              void* d_out, int out_size, void* d_ws, size_t ws_size,
                              hipStream_t stream) {
    const float* x  = (const float*)d_in[0];
    const float* W1 = (const float*)d_in[1];
    const float* b1 = (const float*)d_in[2];
    const float* W2 = (const float*)d_in[3];
    const float* b2 = (const float*)d_in[4];
    const float* W3 = (const float*)d_in[5];
    const float* b3 = (const float*)d_in[6];
    const float* W4 = (const float*)d_in[7];
    const float* b4 = (const float*)d_in[8];
    // d_in[9] = bins (=128), hard-coded

    int*      hist  = (int*)d_ws;                       // 64 KB
    int*      done  = hist + N_IMG * BINS;              // 512 B
    unsigned* flags = (unsigned*)(done + N_IMG);        // 128 imgs * 128 B = 16 KB

    // zero hist + done + flags every call (graph-capturable)
    hipMemsetAsync(d_ws, 0,
                   (size_t)(N_IMG * BINS + N_IMG) * sizeof(int)
                     + (size_t)N_IMG * FLAG_STRIDE * sizeof(unsigned),
                   stream);

    fused_kernel<<<NBLOCKS, 256, 0, stream>>>(x, W1, b1, W2, b2, W3, b3, W4, b4,
                                              (float*)d_out, hist, done, flags);
}

// Round 8
// 350.983 us; speedup vs baseline: 1.7943x; 1.7943x over previous
//
#include <hip/hip_runtime.h>

#define N_IMG 128
#define BINS 128
#define HW_ELEMS (1 << 20)            // 1024*1024 per image
#define BATCH_IMGS 32                 // 32 imgs * 4 MB = 128 MB working set < 256 MB L3
#define NBATCH (N_IMG / BATCH_IMGS)   // 4
#define CHUNKS 32                     // chunk-blocks per image in hist
#define CHUNK_ELEMS (HW_ELEMS / CHUNKS)   // 32768
#define NCOPY 16                      // privatized LDS hist copies
#define HPAD 132                      // 132 % 32 = 4 -> phase-shifted banks

typedef float f32x4 __attribute__((ext_vector_type(4)));

__device__ __forceinline__ int rmw_inc(int* p) {
    return __hip_atomic_fetch_add(p, 1, __ATOMIC_RELAXED, __HIP_MEMORY_SCOPE_AGENT);
}
__device__ __forceinline__ void ag_store(int* p, int v) {
    __hip_atomic_store(p, v, __ATOMIC_RELAXED, __HIP_MEMORY_SCOPE_AGENT);
}
__device__ __forceinline__ int ag_load(const int* p) {
    return __hip_atomic_load(p, __ATOMIC_RELAXED, __HIP_MEMORY_SCOPE_AGENT);
}
__device__ __forceinline__ void ag_store_f(float* p, float v) {
    __hip_atomic_store(p, v, __ATOMIC_RELAXED, __HIP_MEMORY_SCOPE_AGENT);
}

// ---- hist + inline finisher-MLP for one batch of 32 images ----
// 1024 blocks: block -> (img_in_batch = b>>5, chunk = b&31).
// Partial hists stored with agent-scope atomic stores (cross-XCD visible);
// the block whose done[img] increment returns CHUNKS-1 sums partials and
// runs the MLP inline. No spin-waits anywhere.
__global__ __launch_bounds__(256) void hist_mlp_kernel(
    const float* __restrict__ x,
    const float* __restrict__ W1, const float* __restrict__ b1,
    const float* __restrict__ W2, const float* __restrict__ b2,
    const float* __restrict__ W3, const float* __restrict__ b3,
    const float* __restrict__ W4, const float* __restrict__ b4,
    int* __restrict__ parthist, int* __restrict__ done,
    float* __restrict__ wout, int img_base)
{
    __shared__ int   lh[NCOPY * HPAD];
    __shared__ float h0[BINS], a1[32], a2[64], a3[BINS];
    __shared__ int   retsh;

    const int t     = threadIdx.x;
    const int cpy   = t >> 4;                        // 16 lanes per copy
    const int img   = img_base + (blockIdx.x >> 5);  // global image id
    const int chunk = blockIdx.x & (CHUNKS - 1);

    for (int i = t; i < NCOPY * HPAD; i += 256) lh[i] = 0;
    __syncthreads();

    const f32x4* src = (const f32x4*)(x + (size_t)img * HW_ELEMS
                                        + (size_t)chunk * CHUNK_ELEMS);
    const int n4 = CHUNK_ELEMS / 4;                  // 8192
    for (int i = t; i < n4; i += 256) {
        f32x4 v = src[i];
        #pragma unroll
        for (int k = 0; k < 4; ++k) {
            float f = v[k];
            if (f >= 0.0f && f <= 1.0f) {
                int b = (int)(f * 128.0f);
                b = b > 127 ? 127 : b;
                atomicAdd(&lh[cpy * HPAD + b], 1);
            }
        }
    }
    __syncthreads();

    if (t < BINS) {
        int s = 0;
        #pragma unroll
        for (int c = 0; c < NCOPY; ++c) s += lh[c * HPAD + t];
        ag_store(&parthist[((size_t)img * CHUNKS + chunk) * BINS + t], s);
    }
    __syncthreads();                 // vmcnt drain: partial stores complete
    if (t == 0) retsh = rmw_inc(&done[img]);
    __syncthreads();

    if (retsh == CHUNKS - 1) {
        // ---- finisher: all partials visible; run the MLP inline ----
        if (t < BINS) {
            int s = 0;
            #pragma unroll 8
            for (int c = 0; c < CHUNKS; ++c)
                s += ag_load(&parthist[((size_t)img * CHUNKS + c) * BINS + t]);
            h0[t] = (float)s;
        }
        __syncthreads();
        if (t < 32) {
            float acc = b1[t];
            #pragma unroll 8
            for (int i = 0; i < 128; ++i) acc += h0[i] * W1[i * 32 + t];
            a1[t] = fmaxf(acc, 0.0f);
        }
        __syncthreads();
        if (t < 64) {
            float acc = b2[t];
            #pragma unroll 8
            for (int i = 0; i < 32; ++i) acc += a1[i] * W2[i * 64 + t];
            a2[t] = fmaxf(acc, 0.0f);
        }
        __syncthreads();
        if (t < 128) {
            float acc = b3[t];
            #pragma unroll 8
            for (int i = 0; i < 64; ++i) acc += a2[i] * W3[i * 128 + t];
            a3[t] = fmaxf(acc, 0.0f);
        }
        __syncthreads();
        if (t < 64) {
            float p = a3[t] * W4[t] + a3[t + 64] * W4[t + 64];
            #pragma unroll
            for (int off = 32; off > 0; off >>= 1)
                p += __shfl_down(p, off, 64);
            if (t == 0) ag_store_f(&wout[img], p + b4[0]);
        }
    }
}

// ---- scale one batch: out = x * w[img]; reads hit L3 (just touched by hist) ----
__global__ __launch_bounds__(256) void scale_kernel(
    const float* __restrict__ x, const float* __restrict__ w,
    float* __restrict__ out, long long base4, long long n4)
{
    const long long stride = (long long)gridDim.x * blockDim.x;
    const f32x4* xv = (const f32x4*)x;
    f32x4* ov = (f32x4*)out;
    for (long long i = (long long)blockIdx.x * blockDim.x + threadIdx.x;
         i < n4; i += stride) {
        long long gi = base4 + i;
        float s = w[(int)(gi >> 18)];        // 2^18 float4 per image
        f32x4 v = xv[gi];
        v *= s;
        __builtin_nontemporal_store(v, &ov[gi]);  // no-allocate: don't evict batch tail
    }
}

extern "C" void kernel_launch(void* const* d_in, const int* in_sizes, int n_in,
                              void* d_out, int out_size, void* d_ws, size_t ws_size,
                              hipStream_t stream) {
    const float* x  = (const float*)d_in[0];
    const float* W1 = (const float*)d_in[1];
    const float* b1 = (const float*)d_in[2];
    const float* W2 = (const float*)d_in[3];
    const float* b2 = (const float*)d_in[4];
    const float* W3 = (const float*)d_in[5];
    const float* b3 = (const float*)d_in[6];
    const float* W4 = (const float*)d_in[7];
    const float* b4 = (const float*)d_in[8];
    // d_in[9] = bins (=128), hard-coded

    int*   done     = (int*)d_ws;                          // 512 B (zeroed each call)
    int*   parthist = done + N_IMG;                        // 128*32*128*4 = 2 MB (fully overwritten)
    float* wout     = (float*)(parthist + (size_t)N_IMG * CHUNKS * BINS);  // 512 B (overwritten)

    hipMemsetAsync(done, 0, N_IMG * sizeof(int), stream);

    const long long batch4 = (long long)BATCH_IMGS * HW_ELEMS / 4;  // 8M float4
    for (int b = 0; b < NBATCH; ++b) {
        hist_mlp_kernel<<<BATCH_IMGS * CHUNKS, 256, 0, stream>>>(
            x, W1, b1, W2, b2, W3, b3, W4, b4,
            parthist, done, wout, b * BATCH_IMGS);
        scale_kernel<<<2048, 256, 0, stream>>>(
            x, wout, (float*)d_out, (long long)b * batch4, batch4);
    }
}